// Round 5
// baseline (1980.803 us; speedup 1.0000x reference)
//
#include <hip/hip_runtime.h>
#include <hip/hip_bf16.h>
#include <cstddef>

#define N_  20000
#define E_  320000
#define FI_ 16
#define H_  100
#define T_  5
#define FO_ 20
#define B_  50
#define EPSF 1e-5f
#define PT_TM 128   // k_post m-tile
#define PR_  200    // k_pool rows per block

// ---------------- graph prep ----------------
__global__ void k_count(const int* __restrict__ dst, int* __restrict__ cnt) {
  int e = blockIdx.x * blockDim.x + threadIdx.x;
  if (e < E_) atomicAdd(&cnt[dst[e]], 1);
}

__global__ __launch_bounds__(1024) void k_scan(const int* __restrict__ cnt, int* __restrict__ rowptr) {
  __shared__ int ls[1024];
  const int tid = threadIdx.x;
  int carry = 0;
  for (int start = 0; start < N_; start += 1024) {
    int i = start + tid;
    int v = (i < N_) ? cnt[i] : 0;
    ls[tid] = v;
    __syncthreads();
    for (int off = 1; off < 1024; off <<= 1) {
      int t = (tid >= off) ? ls[tid - off] : 0;
      __syncthreads();
      ls[tid] += t;
      __syncthreads();
    }
    if (i < N_) rowptr[i] = carry + ls[tid] - v;   // exclusive scan
    carry += ls[1023];
    __syncthreads();
  }
  if (tid == 0) rowptr[N_] = carry;
}

__global__ void k_fill(const int* __restrict__ dst, const int* __restrict__ rowptr,
                       int* __restrict__ cursor, int* __restrict__ cols) {
  int e = blockIdx.x * blockDim.x + threadIdx.x;
  if (e < E_) {
    int v = dst[e];
    int p = atomicAdd(&cursor[v], 1);
    cols[rowptr[v] + p] = e;
  }
}

__global__ void k_sumlog(const int* __restrict__ cnt, float* __restrict__ sumlog) {
  int i = blockIdx.x * blockDim.x + threadIdx.x;
  float v = (i < N_) ? logf((float)cnt[i] + 1.0f) : 0.0f;
  #pragma unroll
  for (int off = 32; off > 0; off >>= 1) v += __shfl_down(v, off);
  __shared__ float red[4];
  if ((threadIdx.x & 63) == 0) red[threadIdx.x >> 6] = v;
  __syncthreads();
  if (threadIdx.x == 0) atomicAdd(sumlog, red[0] + red[1] + red[2] + red[3]);
}

__global__ void k_scal(const int* __restrict__ cnt, const float* __restrict__ sumlog,
                       float* __restrict__ scal) {
  int i = blockIdx.x * blockDim.x + threadIdx.x;
  if (i >= N_) return;
  float c  = (float)cnt[i];
  float d  = fmaxf(c, 1.0f);
  float ld = logf(d + 1.0f);
  float avg_log = sumlog[0] * (1.0f / (float)N_);
  float avg_lin = (float)E_ / (float)N_;
  scal[i*4+0] = 1.0f;
  scal[i*4+1] = ld / avg_log;
  scal[i*4+2] = avg_log / ld;
  scal[i*4+3] = d / avg_lin;
}

// ---------------- per-layer prep ----------------
__global__ void k_edgevec(const float* __restrict__ pw, const float* __restrict__ pb,
                          const float* __restrict__ ew, const float* __restrict__ eb,
                          float* __restrict__ vec_e, float* __restrict__ cst_e, int f, int C) {
  int c = blockIdx.x * blockDim.x + threadIdx.x;
  if (c >= C) return;
  int t = c / f, g = c - t*f;
  const float* wp = pw + (size_t)t*3*f*f + (size_t)2*f*f + g;
  float v = 0.f, s = 0.f;
  for (int ff = 0; ff < f; ++ff) { float wv = wp[(size_t)ff*f]; v += ew[ff]*wv; s += eb[ff]*wv; }
  vec_e[c] = v;
  cst_e[c] = s + pb[c];
}

__global__ void k_pack_pre(const float* __restrict__ pw, float* __restrict__ Bp, int f, int C) {
  int idx = blockIdx.x * blockDim.x + threadIdx.x;
  int tot = f * 2 * C;
  if (idx >= tot) return;
  int k = idx / (2*C);
  int c = idx - k*(2*C);
  int half = c / C;
  int cc = c - half*C;
  int t = cc / f, g = cc - t*f;
  Bp[idx] = pw[(size_t)t*3*f*f + (size_t)(half*f + k)*f + g];
}

// Repack post weights: Wp[t][c][kk][s][g], 1280 floats per (t,c) chunk,
// layout identical to the k_post2 LDS Bs tile -> staging is a straight copy.
// chunks c < nc1 cover the x@w_x part (s==0 only, zero-padded past f);
// chunks c >= nc1 cover the 4-scaler agg part (k2 = (c-nc1)*16+kk in [0,4f)).
__global__ void k_pack_post(const float* __restrict__ qw, float* __restrict__ Wp, int f) {
  const int nc1 = (f + 15) >> 4;
  const int NC  = nc1 + (f >> 2);
  const int tot = T_ * NC * 1280;
  int idx = blockIdx.x * blockDim.x + threadIdx.x;
  if (idx >= tot) return;
  int g  = idx % FO_;
  int r  = idx / FO_;
  int s  = r & 3;
  int r2 = r >> 2;
  int kk = r2 & 15;
  int r3 = r2 >> 4;
  int c  = r3 % NC;
  int t  = r3 / NC;
  float v;
  if (c < nc1) {
    int k = c*16 + kk;
    v = (s == 0 && k < f) ? qw[((size_t)t*17*f + k) * FO_ + g] : 0.f;
  } else {
    int k2 = (c - nc1)*16 + kk;
    v = qw[((size_t)t*17*f + f + (size_t)s*4*f + k2) * FO_ + g];
  }
  Wp[idx] = v;
}

// ---------------- generic tiled fp32 GEMM: C = A(MxK) @ B(KxNc) (+bias) ----------------
__global__ __launch_bounds__(256) void k_gemm(
    const float* __restrict__ A, const float* __restrict__ Bm,
    const float* __restrict__ bias, float* __restrict__ Cm,
    int M, int K, int Nc)
{
  __shared__ __align__(16) float As[16][68];
  __shared__ __align__(16) float Bs[16][64];
  const int tid = threadIdx.x;
  const int bm = blockIdx.x * 64;
  const int bn = blockIdx.y * 64;
  const int mg = tid & 15;
  const int ng = tid >> 4;
  float acc[4][4];
  #pragma unroll
  for (int i = 0; i < 4; ++i)
    #pragma unroll
    for (int j = 0; j < 4; ++j) acc[i][j] = 0.f;

  for (int k0 = 0; k0 < K; k0 += 16) {
    {
      int kk = tid & 15, mr = tid >> 4;
      #pragma unroll
      for (int p = 0; p < 4; ++p) {
        int m = mr + p*16;
        int gm = bm + m, gk = k0 + kk;
        As[kk][m] = (gm < M && gk < K) ? A[(size_t)gm*K + gk] : 0.f;
      }
      int nn = tid & 63, kr = tid >> 6;
      #pragma unroll
      for (int p = 0; p < 4; ++p) {
        int k = kr + p*4;
        int gk = k0 + k, gn = bn + nn;
        Bs[k][nn] = (gk < K && gn < Nc) ? Bm[(size_t)gk*Nc + gn] : 0.f;
      }
    }
    __syncthreads();
    #pragma unroll
    for (int kk = 0; kk < 16; ++kk) {
      const float4 a = *(const float4*)&As[kk][mg*4];
      const float4 b = *(const float4*)&Bs[kk][ng*4];
      const float av[4] = {a.x, a.y, a.z, a.w};
      const float bv[4] = {b.x, b.y, b.z, b.w};
      #pragma unroll
      for (int i = 0; i < 4; ++i)
        #pragma unroll
        for (int j = 0; j < 4; ++j)
          acc[i][j] = fmaf(av[i], bv[j], acc[i][j]);
    }
    __syncthreads();
  }
  #pragma unroll
  for (int i = 0; i < 4; ++i) {
    int gm = bm + mg*4 + i;
    if (gm >= M) continue;
    #pragma unroll
    for (int j = 0; j < 4; ++j) {
      int gn = bn + ng*4 + j;
      if (gn < Nc) {
        float v = acc[i][j];
        if (bias) v += bias[gn];
        Cm[(size_t)gm*Nc + gn] = v;
      }
    }
  }
}

// ---------------- per-node aggregation ----------------
__global__ __launch_bounds__(256) void k_agg(
    const float* __restrict__ XIJ, const int* __restrict__ rowptr,
    const int* __restrict__ cols, const int* __restrict__ srcArr,
    const float* __restrict__ ea, const float* __restrict__ vec_e,
    const float* __restrict__ cst_e, float* __restrict__ agg, int f, int C)
{
  __shared__ float vsh[512];
  for (int c = threadIdx.x; c < C; c += 256) vsh[c] = vec_e[c];
  __syncthreads();
  const int v = blockIdx.x;
  const int start = rowptr[v], end = rowptr[v+1];
  const int C2 = 2*C;
  float s1[2] = {0.f, 0.f}, s2[2] = {0.f, 0.f};
  float mn[2] = {1e30f, 1e30f}, mx[2] = {-1e30f, -1e30f};
  for (int p = start; p < end; ++p) {
    int e = cols[p];
    int s = srcArr[e];
    float a = ea[e];
    const float* xj = XIJ + (size_t)s * C2 + C;
    #pragma unroll
    for (int i = 0; i < 2; ++i) {
      int c = threadIdx.x + i*256;
      if (c < C) {
        float y = xj[c] + a * vsh[c];
        s1[i] += y; s2[i] += y*y;
        mn[i] = fminf(mn[i], y); mx[i] = fmaxf(mx[i], y);
      }
    }
  }
  const int dcnt = end - start;
  const float* xi = XIJ + (size_t)v * C2;
  float* ag = agg + (size_t)v * 4 * C;
  #pragma unroll
  for (int i = 0; i < 2; ++i) {
    int c = threadIdx.x + i*256;
    if (c < C) {
      int t = c / f, ff = c - t*f;
      float base = xi[c] + cst_e[c];
      float vmean, vsd, vmn, vmx;
      if (dcnt > 0) {
        float inv = 1.0f / (float)dcnt;
        float m1 = s1[i] * inv;
        vmean = base + m1;
        float var = s2[i]*inv - m1*m1;
        vsd = sqrtf(fmaxf(var, 0.f) + EPSF);
        vmn = base + mn[i];
        vmx = base + mx[i];
      } else {
        vmean = 0.f; vsd = sqrtf(EPSF); vmn = 0.f; vmx = 0.f;
      }
      float* o = ag + (size_t)t*4*f + ff;
      o[0]      = vmean;
      o[f]      = vmn;
      o[2*f]    = vmx;
      o[3*f]    = vsd;
    }
  }
}

// ---------------- post transform: h[n, t*FO+g] ----------------
// TM=128 nodes/block, 320 threads: mg=tid&31 owns 4 nodes (float4),
// gg=tid>>5 in [0,10) owns 2 outputs x 4 scalers. grid=(157,5).
// Double-buffered LDS; repacked weights (Wp) -> coalesced float4 staging.
// Per chunk: barrier -> issue next-chunk global loads (regs) ->
// compute current -> ds_write next into other buffer (vmcnt lands here).
__global__ __launch_bounds__(320) void k_post2(
    const float* __restrict__ x, const float* __restrict__ agg,
    const float* __restrict__ scal, const float* __restrict__ Wp,
    const float* __restrict__ qb, float* __restrict__ h, int f)
{
  const int t   = blockIdx.y;
  const int m0  = blockIdx.x * PT_TM;
  const int tid = threadIdx.x;
  const int mg  = tid & 31;
  const int gg  = tid >> 5;          // 0..9, outputs gg*2, gg*2+1
  const int nc1 = (f + 15) >> 4;
  const int NC  = nc1 + (f >> 2);
  const int C4  = 4 * f * T_;
  const int aoff = t * 4 * f;
  const float* wp = Wp + (size_t)t * NC * 1280;

  __shared__ __align__(16) float As[2][16][132];
  __shared__ __align__(16) float Bs[2][1280];

  float acc[4][4][2];
  #pragma unroll
  for (int s = 0; s < 4; ++s)
    #pragma unroll
    for (int j = 0; j < 4; ++j)
      #pragma unroll
      for (int g = 0; g < 2; ++g) acc[s][j][g] = 0.f;

  float4 ra0, ra1, rb;

  auto LOADR = [&](int c) {
    // As tile: 128 nodes x 16 k = 512 float4; idx = tid + p*320
    #pragma unroll
    for (int p = 0; p < 2; ++p) {
      int idx = tid + p*320;
      float4 v = {0.f, 0.f, 0.f, 0.f};
      if (idx < 512) {
        int mm = idx >> 2, q = idx & 3;
        int gm = m0 + mm;
        if (gm < N_) {
          if (c < nc1) {
            int k = c*16 + q*4;
            if (k + 4 <= f) v = *(const float4*)&x[(size_t)gm*f + k];
          } else {
            int k2 = (c - nc1)*16 + q*4;
            v = *(const float4*)&agg[(size_t)gm*C4 + aoff + k2];
          }
        }
      }
      if (p == 0) ra0 = v; else ra1 = v;
    }
    rb = *(const float4*)&wp[(size_t)c*1280 + tid*4];   // coalesced
  };

  auto WRITE = [&](int b) {
    #pragma unroll
    for (int p = 0; p < 2; ++p) {
      int idx = tid + p*320;
      if (idx < 512) {
        int mm = idx >> 2, q = idx & 3;
        float4 v = (p == 0) ? ra0 : ra1;
        As[b][q*4+0][mm] = v.x;
        As[b][q*4+1][mm] = v.y;
        As[b][q*4+2][mm] = v.z;
        As[b][q*4+3][mm] = v.w;
      }
    }
    *(float4*)&Bs[b][tid*4] = rb;                        // layout-matched
  };

  LOADR(0); WRITE(0);
  int cur = 0;
  for (int c = 0; c < NC; ++c) {
    __syncthreads();                 // prev WRITE visible; nothing in vmcnt
    if (c + 1 < NC) LOADR(c + 1);    // issue early — hides under compute
    #pragma unroll
    for (int kk = 0; kk < 16; ++kk) {
      const float4 a = *(const float4*)&As[cur][kk][mg*4];
      const float av[4] = {a.x, a.y, a.z, a.w};
      #pragma unroll
      for (int s = 0; s < 4; ++s) {
        const float2 b = *(const float2*)&Bs[cur][kk*80 + s*20 + gg*2];
        const float bv[2] = {b.x, b.y};
        #pragma unroll
        for (int j = 0; j < 4; ++j)
          #pragma unroll
          for (int g = 0; g < 2; ++g)
            acc[s][j][g] = fmaf(av[j], bv[g], acc[s][j][g]);
      }
    }
    if (c + 1 < NC) WRITE(cur ^ 1);  // write-late into other buffer
    cur ^= 1;
  }

  // finalize: h = acc0 + s1*acc1 + s2*acc2 + s3*acc3 + qb
  #pragma unroll
  for (int j = 0; j < 4; ++j) {
    int gm = m0 + mg*4 + j;
    if (gm >= N_) continue;
    const float sc1 = scal[gm*4+1], sc2 = scal[gm*4+2], sc3 = scal[gm*4+3];
    #pragma unroll
    for (int g = 0; g < 2; ++g) {
      int go = gg*2 + g;
      float vv = acc[0][j][g] + sc1*acc[1][j][g] + sc2*acc[2][j][g] + sc3*acc[3][j][g]
               + qb[t*FO_ + go];
      h[(size_t)gm * (T_*FO_) + t*FO_ + go] = vv;
    }
  }
}

// ---------------- batch norm ----------------
__global__ __launch_bounds__(256) void k_bnsum(const float* __restrict__ h2, float* __restrict__ bnsum) {
  const int tid  = threadIdx.x;
  const int c    = tid & 127;
  const int half = tid >> 7;
  if (c >= H_) return;
  float s = 0.f, s2 = 0.f;
  for (int r = blockIdx.x * 2 + half; r < N_; r += 256) {
    float v = h2[(size_t)r * H_ + c];
    s += v; s2 = fmaf(v, v, s2);
  }
  atomicAdd(&bnsum[c], s);
  atomicAdd(&bnsum[H_ + c], s2);
}

__global__ void k_bnapply(const float* __restrict__ h2, const float* __restrict__ bnsum,
                          const float* __restrict__ gam, const float* __restrict__ bet,
                          float* __restrict__ out) {
  size_t i = (size_t)blockIdx.x * blockDim.x + threadIdx.x;
  if (i >= (size_t)N_*H_) return;
  int c = (int)(i % H_);
  const float invn = 1.0f / (float)N_;
  float mu  = bnsum[c] * invn;
  float var = bnsum[H_ + c] * invn - mu*mu;
  float y = (h2[i] - mu) * rsqrtf(var + EPSF) * gam[c] + bet[c];
  out[i] = fmaxf(y, 0.f);
}

// ---------------- pooling + MLP ----------------
__global__ __launch_bounds__(256) void k_pool(const float* __restrict__ xc, const int* __restrict__ batch,
                                              float* __restrict__ gsum) {
  __shared__ float P[B_][H_];
  const int tid = threadIdx.x;
  for (int i = tid; i < B_*H_; i += 256) P[i / H_][i % H_] = 0.f;
  __syncthreads();
  const int r0 = blockIdx.x * PR_;
  const int rend = (r0 + PR_ < N_) ? r0 + PR_ : N_;
  const int nel = (rend - r0) * H_;
  for (int idx = tid; idx < nel; idx += 256) {
    int rr = idx / H_, c = idx - rr*H_;
    int n = r0 + rr;
    atomicAdd(&P[batch[n]][c], xc[(size_t)n*H_ + c]);
  }
  __syncthreads();
  const int blo = batch[r0], bhi = batch[rend-1];
  const int nb = (bhi - blo + 1) * H_;
  for (int idx = tid; idx < nb; idx += 256) {
    int b = blo + idx / H_, c = idx % H_;
    atomicAdd(&gsum[(size_t)b*H_ + c], P[b][c]);
  }
}

__global__ void k_gcnt(const int* __restrict__ batch, int* __restrict__ gcnt) {
  int n = blockIdx.x * blockDim.x + threadIdx.x;
  if (n < N_) atomicAdd(&gcnt[batch[n]], 1);
}

__global__ __launch_bounds__(512) void k_mlp(
    const float* __restrict__ gsum, const int* __restrict__ gcnt,
    const float* __restrict__ w1, const float* __restrict__ b1,
    const float* __restrict__ w2, const float* __restrict__ b2,
    const float* __restrict__ w3, const float* __restrict__ b3,
    float* __restrict__ out)
{
  __shared__ float G[B_][H_];
  __shared__ float A1[B_][50];
  __shared__ float A2[B_][25];
  const int tid = threadIdx.x;
  for (int i = tid; i < B_*H_; i += 512) {
    int r = i / H_;
    G[r][i - r*H_] = gsum[i] / fmaxf((float)gcnt[r], 1.0f);
  }
  __syncthreads();
  for (int i = tid; i < B_*50; i += 512) {
    int r = i / 50, c = i - r*50;
    float a = b1[c];
    for (int k = 0; k < H_; ++k) a = fmaf(G[r][k], w1[k*50 + c], a);
    A1[r][c] = fmaxf(a, 0.f);
  }
  __syncthreads();
  for (int i = tid; i < B_*25; i += 512) {
    int r = i / 25, c = i - r*25;
    float a = b2[c];
    for (int k = 0; k < 50; ++k) a = fmaf(A1[r][k], w2[k*25 + c], a);
    A2[r][c] = fmaxf(a, 0.f);
  }
  __syncthreads();
  for (int i = tid; i < B_; i += 512) {
    float a = b3[0];
    for (int k = 0; k < 25; ++k) a = fmaf(A2[i][k], w3[k], a);
    out[i] = a;   // float32 output — reference output dtype is f32
  }
}

// ---------------- host ----------------
extern "C" void kernel_launch(void* const* d_in, const int* in_sizes, int n_in,
                              void* d_out, int out_size, void* d_ws, size_t ws_size,
                              hipStream_t stream)
{
  (void)in_sizes; (void)n_in; (void)out_size;
  const float* x0   = (const float*)d_in[0];
  const int*   eidx = (const int*)  d_in[1];
  const float* ea   = (const float*)d_in[2];
  const int*   batch= (const int*)  d_in[3];
  const float* e0w  = (const float*)d_in[4];
  const float* e0b  = (const float*)d_in[5];
  const float* p0w  = (const float*)d_in[6];
  const float* p0b  = (const float*)d_in[7];
  const float* q0w  = (const float*)d_in[8];
  const float* q0b  = (const float*)d_in[9];
  const float* l0w  = (const float*)d_in[10];
  const float* l0b  = (const float*)d_in[11];
  const float* g0   = (const float*)d_in[12];
  const float* b0   = (const float*)d_in[13];
  const float* eLw  = (const float*)d_in[14];
  const float* eLb  = (const float*)d_in[15];
  const float* pLw  = (const float*)d_in[16];
  const float* pLb  = (const float*)d_in[17];
  const float* qLw  = (const float*)d_in[18];
  const float* qLb  = (const float*)d_in[19];
  const float* lLw  = (const float*)d_in[20];
  const float* lLb  = (const float*)d_in[21];
  const float* gL   = (const float*)d_in[22];
  const float* bL   = (const float*)d_in[23];
  const float* w1   = (const float*)d_in[24];
  const float* b1   = (const float*)d_in[25];
  const float* w2   = (const float*)d_in[26];
  const float* b2   = (const float*)d_in[27];
  const float* w3   = (const float*)d_in[28];
  const float* b3   = (const float*)d_in[29];

  const int* src = eidx;
  const int* dst = eidx + E_;

  char* w = (char*)d_ws;
  size_t off = 0;
  auto take = [&](size_t bytes) -> void* {
    void* p = (void*)(w + off);
    off = (off + bytes + 255) & ~(size_t)255;
    return p;
  };
  int*   cnt    = (int*)  take((size_t)N_*4);
  int*   rowptr = (int*)  take((size_t)(N_+1)*4);
  int*   cursor = (int*)  take((size_t)N_*4);
  int*   cols   = (int*)  take((size_t)E_*4);
  float* scal   = (float*)take((size_t)N_*16);
  float* sumlog = (float*)take(256);
  float* bnsum  = (float*)take((size_t)2*H_*4);
  float* vec_e  = (float*)take((size_t)T_*H_*4);
  float* cst_e  = (float*)take((size_t)T_*H_*4);
  float* Bpre   = (float*)take((size_t)H_*2*T_*H_*4);
  float* Wp     = (float*)take((size_t)T_*32*1280*4);   // repacked post weights
  float* XIJ    = (float*)take((size_t)N_*2*T_*H_*4);   // 80 MB
  float* aggb   = (float*)take((size_t)N_*4*T_*H_*4);   // 160 MB
  float* hbuf   = (float*)take((size_t)N_*H_*4);
  float* h2buf  = (float*)take((size_t)N_*H_*4);
  float* xcur   = (float*)take((size_t)N_*H_*4);
  float* gsum   = (float*)take((size_t)B_*H_*4);
  int*   gcnt   = (int*)  take((size_t)B_*4);
  if (off > ws_size) return;   // workspace too small: bail (test fails loudly)

  hipMemsetAsync(cnt,    0, (size_t)N_*4, stream);
  hipMemsetAsync(cursor, 0, (size_t)N_*4, stream);
  hipMemsetAsync(sumlog, 0, 4, stream);
  hipMemsetAsync(gsum,   0, (size_t)B_*H_*4, stream);
  hipMemsetAsync(gcnt,   0, (size_t)B_*4, stream);

  k_count <<<dim3((E_+255)/256), dim3(256), 0, stream>>>(dst, cnt);
  k_scan  <<<dim3(1),            dim3(1024),0, stream>>>(cnt, rowptr);
  k_fill  <<<dim3((E_+255)/256), dim3(256), 0, stream>>>(dst, rowptr, cursor, cols);
  k_sumlog<<<dim3((N_+255)/256), dim3(256), 0, stream>>>(cnt, sumlog);
  k_scal  <<<dim3((N_+255)/256), dim3(256), 0, stream>>>(cnt, sumlog, scal);

  auto layer = [&](const float* xin, int f,
                   const float* ew, const float* eb, const float* pw, const float* pb,
                   const float* qw, const float* qb, const float* lw, const float* lb,
                   const float* bg, const float* bb) {
    const int C = T_ * f;
    k_edgevec<<<dim3((C+255)/256), dim3(256), 0, stream>>>(pw, pb, ew, eb, vec_e, cst_e, f, C);
    const int pe = f * 2 * C;
    k_pack_pre<<<dim3((pe+255)/256), dim3(256), 0, stream>>>(pw, Bpre, f, C);
    const int nc1 = (f + 15) >> 4;
    const int NC  = nc1 + (f >> 2);
    const int wtot = T_ * NC * 1280;
    k_pack_post<<<dim3((wtot+255)/256), dim3(256), 0, stream>>>(qw, Wp, f);
    k_gemm<<<dim3((N_+63)/64, (2*C+63)/64), dim3(256), 0, stream>>>(xin, Bpre, nullptr, XIJ, N_, f, 2*C);
    k_agg<<<dim3(N_), dim3(256), 0, stream>>>(XIJ, rowptr, cols, src, ea, vec_e, cst_e, aggb, f, C);
    k_post2<<<dim3((N_+PT_TM-1)/PT_TM, T_), dim3(320), 0, stream>>>(xin, aggb, scal, Wp, qb, hbuf, f);
    k_gemm<<<dim3((N_+63)/64, (H_+63)/64), dim3(256), 0, stream>>>(hbuf, lw, lb, h2buf, N_, H_, H_);
    hipMemsetAsync(bnsum, 0, (size_t)2*H_*4, stream);
    k_bnsum<<<dim3(128), dim3(256), 0, stream>>>(h2buf, bnsum);
    k_bnapply<<<dim3((unsigned)(((size_t)N_*H_+255)/256)), dim3(256), 0, stream>>>(h2buf, bnsum, bg, bb, xcur);
  };

  layer(x0,   FI_, e0w, e0b, p0w, p0b, q0w, q0b, l0w, l0b, g0, b0);
  layer(xcur, H_,  eLw, eLb, pLw, pLb, qLw, qLb, lLw, lLb, gL, bL);
  layer(xcur, H_,  eLw + H_, eLb + H_,
        pLw + (size_t)T_*3*H_*H_, pLb + T_*H_,
        qLw + (size_t)T_*17*H_*FO_, qLb + T_*FO_,
        lLw + H_*H_, lLb + H_, gL + H_, bL + H_);

  k_pool<<<dim3((N_+PR_-1)/PR_), dim3(256), 0, stream>>>(xcur, batch, gsum);
  k_gcnt<<<dim3((N_+255)/256), dim3(256), 0, stream>>>(batch, gcnt);
  k_mlp <<<dim3(1), dim3(512), 0, stream>>>(gsum, gcnt, w1, b1, w2, b2, w3, b3, (float*)d_out);
}

// Round 6
// 1458.813 us; speedup vs baseline: 1.3578x; 1.3578x over previous
//
#include <hip/hip_runtime.h>
#include <hip/hip_bf16.h>
#include <cstddef>

#define N_  20000
#define E_  320000
#define FI_ 16
#define H_  100
#define T_  5
#define FO_ 20
#define B_  50
#define EPSF 1e-5f
#define PR_  200    // k_pool rows per block

typedef __attribute__((ext_vector_type(8))) short short8;
typedef __attribute__((ext_vector_type(4))) float f32x4;

static __device__ __forceinline__ unsigned short f2bf(float x) {
  unsigned int u = __builtin_bit_cast(unsigned int, x);
  unsigned int r = (u + 0x7FFFu + ((u >> 16) & 1u)) >> 16;   // RNE
  return (unsigned short)r;
}

// ---------------- graph prep ----------------
__global__ void k_count(const int* __restrict__ dst, int* __restrict__ cnt) {
  int e = blockIdx.x * blockDim.x + threadIdx.x;
  if (e < E_) atomicAdd(&cnt[dst[e]], 1);
}

__global__ __launch_bounds__(1024) void k_scan(const int* __restrict__ cnt, int* __restrict__ rowptr) {
  __shared__ int ls[1024];
  const int tid = threadIdx.x;
  int carry = 0;
  for (int start = 0; start < N_; start += 1024) {
    int i = start + tid;
    int v = (i < N_) ? cnt[i] : 0;
    ls[tid] = v;
    __syncthreads();
    for (int off = 1; off < 1024; off <<= 1) {
      int t = (tid >= off) ? ls[tid - off] : 0;
      __syncthreads();
      ls[tid] += t;
      __syncthreads();
    }
    if (i < N_) rowptr[i] = carry + ls[tid] - v;   // exclusive scan
    carry += ls[1023];
    __syncthreads();
  }
  if (tid == 0) rowptr[N_] = carry;
}

__global__ void k_fill(const int* __restrict__ dst, const int* __restrict__ rowptr,
                       int* __restrict__ cursor, int* __restrict__ cols) {
  int e = blockIdx.x * blockDim.x + threadIdx.x;
  if (e < E_) {
    int v = dst[e];
    int p = atomicAdd(&cursor[v], 1);
    cols[rowptr[v] + p] = e;
  }
}

__global__ void k_sumlog(const int* __restrict__ cnt, float* __restrict__ sumlog) {
  int i = blockIdx.x * blockDim.x + threadIdx.x;
  float v = (i < N_) ? logf((float)cnt[i] + 1.0f) : 0.0f;
  #pragma unroll
  for (int off = 32; off > 0; off >>= 1) v += __shfl_down(v, off);
  __shared__ float red[4];
  if ((threadIdx.x & 63) == 0) red[threadIdx.x >> 6] = v;
  __syncthreads();
  if (threadIdx.x == 0) atomicAdd(sumlog, red[0] + red[1] + red[2] + red[3]);
}

__global__ void k_scal(const int* __restrict__ cnt, const float* __restrict__ sumlog,
                       float* __restrict__ scal) {
  int i = blockIdx.x * blockDim.x + threadIdx.x;
  if (i >= N_) return;
  float c  = (float)cnt[i];
  float d  = fmaxf(c, 1.0f);
  float ld = logf(d + 1.0f);
  float avg_log = sumlog[0] * (1.0f / (float)N_);
  float avg_lin = (float)E_ / (float)N_;
  scal[i*4+0] = 1.0f;
  scal[i*4+1] = ld / avg_log;
  scal[i*4+2] = avg_log / ld;
  scal[i*4+3] = d / avg_lin;
}

// ---------------- per-layer prep ----------------
__global__ void k_edgevec(const float* __restrict__ pw, const float* __restrict__ pb,
                          const float* __restrict__ ew, const float* __restrict__ eb,
                          float* __restrict__ vec_e, float* __restrict__ cst_e, int f, int C) {
  int c = blockIdx.x * blockDim.x + threadIdx.x;
  if (c >= C) return;
  int t = c / f, g = c - t*f;
  const float* wp = pw + (size_t)t*3*f*f + (size_t)2*f*f + g;
  float v = 0.f, s = 0.f;
  for (int ff = 0; ff < f; ++ff) { float wv = wp[(size_t)ff*f]; v += ew[ff]*wv; s += eb[ff]*wv; }
  vec_e[c] = v;
  cst_e[c] = s + pb[c];
}

__global__ void k_pack_pre(const float* __restrict__ pw, float* __restrict__ Bp, int f, int C) {
  int idx = blockIdx.x * blockDim.x + threadIdx.x;
  int tot = f * 2 * C;
  if (idx >= tot) return;
  int k = idx / (2*C);
  int c = idx - k*(2*C);
  int half = c / C;
  int cc = c - half*C;
  int t = cc / f, g = cc - t*f;
  Bp[idx] = pw[(size_t)t*3*f*f + (size_t)(half*f + k)*f + g];
}

// Pack post weights transposed, bf16: W2[t][j=s*20+g][k], k in [0,KP).
// k<4f: w_s[t,k,g]; 4f<=k<5f (s==0 only): w_x[t,k-4f,g]; else 0.
__global__ void k_pack_w2(const float* __restrict__ qw, unsigned short* __restrict__ W2,
                          int f, int KP) {
  int tot = T_ * 80 * KP;
  int idx = blockIdx.x * blockDim.x + threadIdx.x;
  if (idx >= tot) return;
  int k = idx % KP;
  int r = idx / KP;
  int j = r % 80;
  int t = r / 80;
  int s = j / 20, g = j - s*20;
  float v = 0.f;
  if (k < 4*f)                 v = qw[((size_t)t*17*f + f + (size_t)s*4*f + k) * FO_ + g];
  else if (k < 5*f && s == 0)  v = qw[((size_t)t*17*f + (k - 4*f)) * FO_ + g];
  W2[idx] = f2bf(v);
}

// ---------------- generic tiled fp32 GEMM: C = A(MxK) @ B(KxNc) (+bias) ----------------
__global__ __launch_bounds__(256) void k_gemm(
    const float* __restrict__ A, const float* __restrict__ Bm,
    const float* __restrict__ bias, float* __restrict__ Cm,
    int M, int K, int Nc)
{
  __shared__ __align__(16) float As[16][68];
  __shared__ __align__(16) float Bs[16][64];
  const int tid = threadIdx.x;
  const int bm = blockIdx.x * 64;
  const int bn = blockIdx.y * 64;
  const int mg = tid & 15;
  const int ng = tid >> 4;
  float acc[4][4];
  #pragma unroll
  for (int i = 0; i < 4; ++i)
    #pragma unroll
    for (int j = 0; j < 4; ++j) acc[i][j] = 0.f;

  for (int k0 = 0; k0 < K; k0 += 16) {
    {
      int kk = tid & 15, mr = tid >> 4;
      #pragma unroll
      for (int p = 0; p < 4; ++p) {
        int m = mr + p*16;
        int gm = bm + m, gk = k0 + kk;
        As[kk][m] = (gm < M && gk < K) ? A[(size_t)gm*K + gk] : 0.f;
      }
      int nn = tid & 63, kr = tid >> 6;
      #pragma unroll
      for (int p = 0; p < 4; ++p) {
        int k = kr + p*4;
        int gk = k0 + k, gn = bn + nn;
        Bs[k][nn] = (gk < K && gn < Nc) ? Bm[(size_t)gk*Nc + gn] : 0.f;
      }
    }
    __syncthreads();
    #pragma unroll
    for (int kk = 0; kk < 16; ++kk) {
      const float4 a = *(const float4*)&As[kk][mg*4];
      const float4 b = *(const float4*)&Bs[kk][ng*4];
      const float av[4] = {a.x, a.y, a.z, a.w};
      const float bv[4] = {b.x, b.y, b.z, b.w};
      #pragma unroll
      for (int i = 0; i < 4; ++i)
        #pragma unroll
        for (int j = 0; j < 4; ++j)
          acc[i][j] = fmaf(av[i], bv[j], acc[i][j]);
    }
    __syncthreads();
  }
  #pragma unroll
  for (int i = 0; i < 4; ++i) {
    int gm = bm + mg*4 + i;
    if (gm >= M) continue;
    #pragma unroll
    for (int j = 0; j < 4; ++j) {
      int gn = bn + ng*4 + j;
      if (gn < Nc) {
        float v = acc[i][j];
        if (bias) v += bias[gn];
        Cm[(size_t)gm*Nc + gn] = v;
      }
    }
  }
}

// ---------------- per-node aggregation -> bf16 Apost rows ----------------
// Apost[n][t][k]: k<4f: stats (mean,min,max,std blocks of f); [4f,5f): x; [5f,KP): 0
__global__ __launch_bounds__(256) void k_agg(
    const float* __restrict__ XIJ, const int* __restrict__ rowptr,
    const int* __restrict__ cols, const int* __restrict__ srcArr,
    const float* __restrict__ ea, const float* __restrict__ vec_e,
    const float* __restrict__ cst_e, const float* __restrict__ xin,
    unsigned short* __restrict__ Apost, int f, int C, int KP)
{
  __shared__ float vsh[512];
  for (int c = threadIdx.x; c < C; c += 256) vsh[c] = vec_e[c];
  __syncthreads();
  const int v = blockIdx.x;
  const int start = rowptr[v], end = rowptr[v+1];
  const int C2 = 2*C;
  float s1[2] = {0.f, 0.f}, s2[2] = {0.f, 0.f};
  float mn[2] = {1e30f, 1e30f}, mx[2] = {-1e30f, -1e30f};
  for (int p = start; p < end; ++p) {
    int e = cols[p];
    int s = srcArr[e];
    float a = ea[e];
    const float* xj = XIJ + (size_t)s * C2 + C;
    #pragma unroll
    for (int i = 0; i < 2; ++i) {
      int c = threadIdx.x + i*256;
      if (c < C) {
        float y = xj[c] + a * vsh[c];
        s1[i] += y; s2[i] += y*y;
        mn[i] = fminf(mn[i], y); mx[i] = fmaxf(mx[i], y);
      }
    }
  }
  const int dcnt = end - start;
  const float* xi = XIJ + (size_t)v * C2;
  #pragma unroll
  for (int i = 0; i < 2; ++i) {
    int c = threadIdx.x + i*256;
    if (c < C) {
      int t = c / f, ff = c - t*f;
      float base = xi[c] + cst_e[c];
      float vmean, vsd, vmn, vmx;
      if (dcnt > 0) {
        float inv = 1.0f / (float)dcnt;
        float m1 = s1[i] * inv;
        vmean = base + m1;
        float var = s2[i]*inv - m1*m1;
        vsd = sqrtf(fmaxf(var, 0.f) + EPSF);
        vmn = base + mn[i];
        vmx = base + mx[i];
      } else {
        vmean = 0.f; vsd = sqrtf(EPSF); vmn = 0.f; vmx = 0.f;
      }
      unsigned short* o = Apost + ((size_t)v * T_ + t) * KP + ff;
      o[0]   = f2bf(vmean);
      o[f]   = f2bf(vmn);
      o[2*f] = f2bf(vmx);
      o[3*f] = f2bf(vsd);
    }
  }
  // x copy (shared by all towers) + zero pad
  const int rem = KP - 4*f;
  for (int idx = threadIdx.x; idx < T_*rem; idx += 256) {
    int t = idx / rem, kk = idx - t*rem;
    int k = 4*f + kk;
    unsigned short val = 0;
    if (k < 5*f) val = f2bf(xin[(size_t)v*f + (k - 4*f)]);
    Apost[((size_t)v * T_ + t) * KP + k] = val;
  }
}

// ---------------- post GEMM via MFMA: P[n][t*80 + s*20+g] ----------------
// grid (ceil(N/128), T). 256 thr = 4 waves; wave w: rows [w*32,w*32+32),
// 2 m-frags x 5 n-frags of 16x16, K-step 32 (bf16 MFMA 16x16x32).
__global__ __launch_bounds__(256) void k_postmm(
    const unsigned short* __restrict__ Apost, const unsigned short* __restrict__ W2,
    float* __restrict__ P, int KP)
{
  const int t    = blockIdx.y;
  const int m0   = blockIdx.x * 128;
  const int tid  = threadIdx.x;
  const int w    = tid >> 6;
  const int lane = tid & 63;
  const int rl   = lane & 15;     // frag row/col
  const int kq   = lane >> 4;     // k-quarter 0..3
  __shared__ __align__(16) unsigned short As[128*40];  // stride 40 (pad)
  __shared__ __align__(16) unsigned short Bs[80*40];
  f32x4 acc[2][5];
  #pragma unroll
  for (int mf = 0; mf < 2; ++mf)
    #pragma unroll
    for (int nf = 0; nf < 5; ++nf) acc[mf][nf] = (f32x4){0.f,0.f,0.f,0.f};

  const unsigned short* wt = W2 + (size_t)t * 80 * KP;

  for (int k0 = 0; k0 < KP; k0 += 32) {
    __syncthreads();
    // stage A: 128 rows x 32 bf16 = 512 chunks of 8
    #pragma unroll
    for (int p = 0; p < 2; ++p) {
      int idx = tid + p*256;
      int row = idx >> 2, q = idx & 3;
      int gm = m0 + row;
      uint4 v = {0u,0u,0u,0u};
      if (gm < N_) v = *(const uint4*)&Apost[((size_t)gm*T_ + t)*KP + k0 + q*8];
      *(uint4*)&As[row*40 + q*8] = v;
    }
    // stage B (transposed): 80 cols x 32 bf16 = 320 chunks of 8
    #pragma unroll
    for (int p = 0; p < 2; ++p) {
      int idx = tid + p*256;
      if (idx < 320) {
        int j = idx >> 2, q = idx & 3;
        uint4 v = *(const uint4*)&wt[(size_t)j*KP + k0 + q*8];
        *(uint4*)&Bs[j*40 + q*8] = v;
      }
    }
    __syncthreads();
    short8 af[2], bf[5];
    #pragma unroll
    for (int mf = 0; mf < 2; ++mf)
      af[mf] = *(const short8*)&As[(w*32 + mf*16 + rl)*40 + kq*8];
    #pragma unroll
    for (int nf = 0; nf < 5; ++nf)
      bf[nf] = *(const short8*)&Bs[(nf*16 + rl)*40 + kq*8];
    #pragma unroll
    for (int mf = 0; mf < 2; ++mf)
      #pragma unroll
      for (int nf = 0; nf < 5; ++nf)
        acc[mf][nf] = __builtin_amdgcn_mfma_f32_16x16x32_bf16(af[mf], bf[nf], acc[mf][nf], 0, 0, 0);
  }
  // C/D layout (m89-verified): col = lane&15, row = (lane>>4)*4 + r
  #pragma unroll
  for (int mf = 0; mf < 2; ++mf)
    #pragma unroll
    for (int nf = 0; nf < 5; ++nf)
      #pragma unroll
      for (int r = 0; r < 4; ++r) {
        int n = m0 + w*32 + mf*16 + kq*4 + r;
        if (n < N_) P[(size_t)n*400 + t*80 + nf*16 + rl] = acc[mf][nf][r];
      }
}

// ---------------- combine: h = P0 + s1*P1 + s2*P2 + s3*P3 + qb ----------------
__global__ void k_comb(const float* __restrict__ P, const float* __restrict__ scal,
                       const float* __restrict__ qb, float* __restrict__ h) {
  int idx = blockIdx.x * blockDim.x + threadIdx.x;
  if (idx >= N_ * (T_*FO_)) return;
  int n = idx / (T_*FO_);
  int c = idx - n * (T_*FO_);
  int t = c / FO_, g = c - t*FO_;
  const float* p = P + (size_t)n*400 + t*80;
  h[idx] = p[g] + scal[n*4+1]*p[20+g] + scal[n*4+2]*p[40+g] + scal[n*4+3]*p[60+g] + qb[c];
}

// ---------------- batch norm ----------------
__global__ __launch_bounds__(256) void k_bnsum(const float* __restrict__ h2, float* __restrict__ bnsum) {
  const int tid  = threadIdx.x;
  const int c    = tid & 127;
  const int half = tid >> 7;
  if (c >= H_) return;
  float s = 0.f, s2 = 0.f;
  for (int r = blockIdx.x * 2 + half; r < N_; r += 256) {
    float v = h2[(size_t)r * H_ + c];
    s += v; s2 = fmaf(v, v, s2);
  }
  atomicAdd(&bnsum[c], s);
  atomicAdd(&bnsum[H_ + c], s2);
}

__global__ void k_bnapply(const float* __restrict__ h2, const float* __restrict__ bnsum,
                          const float* __restrict__ gam, const float* __restrict__ bet,
                          float* __restrict__ out) {
  size_t i = (size_t)blockIdx.x * blockDim.x + threadIdx.x;
  if (i >= (size_t)N_*H_) return;
  int c = (int)(i % H_);
  const float invn = 1.0f / (float)N_;
  float mu  = bnsum[c] * invn;
  float var = bnsum[H_ + c] * invn - mu*mu;
  float y = (h2[i] - mu) * rsqrtf(var + EPSF) * gam[c] + bet[c];
  out[i] = fmaxf(y, 0.f);
}

// ---------------- pooling + MLP ----------------
__global__ __launch_bounds__(256) void k_pool(const float* __restrict__ xc, const int* __restrict__ batch,
                                              float* __restrict__ gsum) {
  __shared__ float Pl[B_][H_];
  const int tid = threadIdx.x;
  for (int i = tid; i < B_*H_; i += 256) Pl[i / H_][i % H_] = 0.f;
  __syncthreads();
  const int r0 = blockIdx.x * PR_;
  const int rend = (r0 + PR_ < N_) ? r0 + PR_ : N_;
  const int nel = (rend - r0) * H_;
  for (int idx = tid; idx < nel; idx += 256) {
    int rr = idx / H_, c = idx - rr*H_;
    int n = r0 + rr;
    atomicAdd(&Pl[batch[n]][c], xc[(size_t)n*H_ + c]);
  }
  __syncthreads();
  const int blo = batch[r0], bhi = batch[rend-1];
  const int nb = (bhi - blo + 1) * H_;
  for (int idx = tid; idx < nb; idx += 256) {
    int b = blo + idx / H_, c = idx % H_;
    atomicAdd(&gsum[(size_t)b*H_ + c], Pl[b][c]);
  }
}

__global__ void k_gcnt(const int* __restrict__ batch, int* __restrict__ gcnt) {
  int n = blockIdx.x * blockDim.x + threadIdx.x;
  if (n < N_) atomicAdd(&gcnt[batch[n]], 1);
}

__global__ __launch_bounds__(512) void k_mlp(
    const float* __restrict__ gsum, const int* __restrict__ gcnt,
    const float* __restrict__ w1, const float* __restrict__ b1,
    const float* __restrict__ w2, const float* __restrict__ b2,
    const float* __restrict__ w3, const float* __restrict__ b3,
    float* __restrict__ out)
{
  __shared__ float G[B_][H_];
  __shared__ float A1[B_][50];
  __shared__ float A2[B_][25];
  const int tid = threadIdx.x;
  for (int i = tid; i < B_*H_; i += 512) {
    int r = i / H_;
    G[r][i - r*H_] = gsum[i] / fmaxf((float)gcnt[r], 1.0f);
  }
  __syncthreads();
  for (int i = tid; i < B_*50; i += 512) {
    int r = i / 50, c = i - r*50;
    float a = b1[c];
    for (int k = 0; k < H_; ++k) a = fmaf(G[r][k], w1[k*50 + c], a);
    A1[r][c] = fmaxf(a, 0.f);
  }
  __syncthreads();
  for (int i = tid; i < B_*25; i += 512) {
    int r = i / 25, c = i - r*25;
    float a = b2[c];
    for (int k = 0; k < 50; ++k) a = fmaf(A1[r][k], w2[k*25 + c], a);
    A2[r][c] = fmaxf(a, 0.f);
  }
  __syncthreads();
  for (int i = tid; i < B_; i += 512) {
    float a = b3[0];
    for (int k = 0; k < 25; ++k) a = fmaf(A2[i][k], w3[k], a);
    out[i] = a;   // float32 output — reference output dtype is f32
  }
}

// ---------------- host ----------------
extern "C" void kernel_launch(void* const* d_in, const int* in_sizes, int n_in,
                              void* d_out, int out_size, void* d_ws, size_t ws_size,
                              hipStream_t stream)
{
  (void)in_sizes; (void)n_in; (void)out_size;
  const float* x0   = (const float*)d_in[0];
  const int*   eidx = (const int*)  d_in[1];
  const float* ea   = (const float*)d_in[2];
  const int*   batch= (const int*)  d_in[3];
  const float* e0w  = (const float*)d_in[4];
  const float* e0b  = (const float*)d_in[5];
  const float* p0w  = (const float*)d_in[6];
  const float* p0b  = (const float*)d_in[7];
  const float* q0w  = (const float*)d_in[8];
  const float* q0b  = (const float*)d_in[9];
  const float* l0w  = (const float*)d_in[10];
  const float* l0b  = (const float*)d_in[11];
  const float* g0   = (const float*)d_in[12];
  const float* b0   = (const float*)d_in[13];
  const float* eLw  = (const float*)d_in[14];
  const float* eLb  = (const float*)d_in[15];
  const float* pLw  = (const float*)d_in[16];
  const float* pLb  = (const float*)d_in[17];
  const float* qLw  = (const float*)d_in[18];
  const float* qLb  = (const float*)d_in[19];
  const float* lLw  = (const float*)d_in[20];
  const float* lLb  = (const float*)d_in[21];
  const float* gL   = (const float*)d_in[22];
  const float* bL   = (const float*)d_in[23];
  const float* w1   = (const float*)d_in[24];
  const float* b1   = (const float*)d_in[25];
  const float* w2   = (const float*)d_in[26];
  const float* b2   = (const float*)d_in[27];
  const float* w3   = (const float*)d_in[28];
  const float* b3   = (const float*)d_in[29];

  const int* src = eidx;
  const int* dst = eidx + E_;

  char* w = (char*)d_ws;
  size_t off = 0;
  auto take = [&](size_t bytes) -> void* {
    void* p = (void*)(w + off);
    off = (off + bytes + 255) & ~(size_t)255;
    return p;
  };
  int*   cnt    = (int*)  take((size_t)N_*4);
  int*   rowptr = (int*)  take((size_t)(N_+1)*4);
  int*   cursor = (int*)  take((size_t)N_*4);
  int*   cols   = (int*)  take((size_t)E_*4);
  float* scal   = (float*)take((size_t)N_*16);
  float* sumlog = (float*)take(256);
  float* bnsum  = (float*)take((size_t)2*H_*4);
  float* vec_e  = (float*)take((size_t)T_*H_*4);
  float* cst_e  = (float*)take((size_t)T_*H_*4);
  float* Bpre   = (float*)take((size_t)H_*2*T_*H_*4);
  unsigned short* W2 = (unsigned short*)take((size_t)T_*80*512*2);
  float* XIJ    = (float*)take((size_t)N_*2*T_*H_*4);        // 80 MB
  unsigned short* Apost = (unsigned short*)take((size_t)N_*T_*512*2);  // 102 MB
  float* Pbuf   = (float*)take((size_t)N_*400*4);            // 32 MB
  float* hbuf   = (float*)take((size_t)N_*H_*4);
  float* h2buf  = (float*)take((size_t)N_*H_*4);
  float* xcur   = (float*)take((size_t)N_*H_*4);
  float* gsum   = (float*)take((size_t)B_*H_*4);
  int*   gcnt   = (int*)  take((size_t)B_*4);
  if (off > ws_size) return;   // workspace too small: bail (test fails loudly)

  hipMemsetAsync(cnt,    0, (size_t)N_*4, stream);
  hipMemsetAsync(cursor, 0, (size_t)N_*4, stream);
  hipMemsetAsync(sumlog, 0, 4, stream);
  hipMemsetAsync(gsum,   0, (size_t)B_*H_*4, stream);
  hipMemsetAsync(gcnt,   0, (size_t)B_*4, stream);

  k_count <<<dim3((E_+255)/256), dim3(256), 0, stream>>>(dst, cnt);
  k_scan  <<<dim3(1),            dim3(1024),0, stream>>>(cnt, rowptr);
  k_fill  <<<dim3((E_+255)/256), dim3(256), 0, stream>>>(dst, rowptr, cursor, cols);
  k_sumlog<<<dim3((N_+255)/256), dim3(256), 0, stream>>>(cnt, sumlog);
  k_scal  <<<dim3((N_+255)/256), dim3(256), 0, stream>>>(cnt, sumlog, scal);

  auto layer = [&](const float* xin, int f,
                   const float* ew, const float* eb, const float* pw, const float* pb,
                   const float* qw, const float* qb, const float* lw, const float* lb,
                   const float* bg, const float* bb) {
    const int C  = T_ * f;
    const int KP = ((5*f + 31) / 32) * 32;   // padded per-tower K (f=16:96, f=100:512)
    k_edgevec<<<dim3((C+255)/256), dim3(256), 0, stream>>>(pw, pb, ew, eb, vec_e, cst_e, f, C);
    const int pe = f * 2 * C;
    k_pack_pre<<<dim3((pe+255)/256), dim3(256), 0, stream>>>(pw, Bpre, f, C);
    const int wtot = T_ * 80 * KP;
    k_pack_w2<<<dim3((wtot+255)/256), dim3(256), 0, stream>>>(qw, W2, f, KP);
    k_gemm<<<dim3((N_+63)/64, (2*C+63)/64), dim3(256), 0, stream>>>(xin, Bpre, nullptr, XIJ, N_, f, 2*C);
    k_agg<<<dim3(N_), dim3(256), 0, stream>>>(XIJ, rowptr, cols, src, ea, vec_e, cst_e, xin, Apost, f, C, KP);
    k_postmm<<<dim3((N_+127)/128, T_), dim3(256), 0, stream>>>(Apost, W2, Pbuf, KP);
    k_comb<<<dim3((N_*T_*FO_+255)/256), dim3(256), 0, stream>>>(Pbuf, scal, qb, hbuf);
    k_gemm<<<dim3((N_+63)/64, (H_+63)/64), dim3(256), 0, stream>>>(hbuf, lw, lb, h2buf, N_, H_, H_);
    hipMemsetAsync(bnsum, 0, (size_t)2*H_*4, stream);
    k_bnsum<<<dim3(128), dim3(256), 0, stream>>>(h2buf, bnsum);
    k_bnapply<<<dim3((unsigned)(((size_t)N_*H_+255)/256)), dim3(256), 0, stream>>>(h2buf, bnsum, bg, bb, xcur);
  };

  layer(x0,   FI_, e0w, e0b, p0w, p0b, q0w, q0b, l0w, l0b, g0, b0);
  layer(xcur, H_,  eLw, eLb, pLw, pLb, qLw, qLb, lLw, lLb, gL, bL);
  layer(xcur, H_,  eLw + H_, eLb + H_,
        pLw + (size_t)T_*3*H_*H_, pLb + T_*H_,
        qLw + (size_t)T_*17*H_*FO_, qLb + T_*FO_,
        lLw + H_*H_, lLb + H_, gL + H_, bL + H_);

  k_pool<<<dim3((N_+PR_-1)/PR_), dim3(256), 0, stream>>>(xcur, batch, gsum);
  k_gcnt<<<dim3((N_+255)/256), dim3(256), 0, stream>>>(batch, gcnt);
  k_mlp <<<dim3(1), dim3(512), 0, stream>>>(gsum, gcnt, w1, b1, w2, b2, w3, b3, (float*)d_out);
}

// Round 7
// 1338.476 us; speedup vs baseline: 1.4799x; 1.0899x over previous
//
#include <hip/hip_runtime.h>
#include <hip/hip_bf16.h>
#include <cstddef>

#define N_  20000
#define E_  320000
#define FI_ 16
#define H_  100
#define T_  5
#define FO_ 20
#define B_  50
#define EPSF 1e-5f
#define PR_  200    // k_pool rows per block

typedef __attribute__((ext_vector_type(8))) short short8;
typedef __attribute__((ext_vector_type(4))) float f32x4;

static __device__ __forceinline__ unsigned short f2bf(float x) {
  unsigned int u = __builtin_bit_cast(unsigned int, x);
  unsigned int r = (u + 0x7FFFu + ((u >> 16) & 1u)) >> 16;   // RNE
  return (unsigned short)r;
}
static __device__ __forceinline__ float bf2f_lo(unsigned int u) {
  return __builtin_bit_cast(float, (u & 0xFFFFu) << 16);
}
static __device__ __forceinline__ float bf2f_hi(unsigned int u) {
  return __builtin_bit_cast(float, u & 0xFFFF0000u);
}

// ---------------- graph prep ----------------
__global__ void k_count(const int* __restrict__ dst, int* __restrict__ cnt) {
  int e = blockIdx.x * blockDim.x + threadIdx.x;
  if (e < E_) atomicAdd(&cnt[dst[e]], 1);
}

__global__ __launch_bounds__(1024) void k_scan(const int* __restrict__ cnt, int* __restrict__ rowptr) {
  __shared__ int ls[1024];
  const int tid = threadIdx.x;
  int carry = 0;
  for (int start = 0; start < N_; start += 1024) {
    int i = start + tid;
    int v = (i < N_) ? cnt[i] : 0;
    ls[tid] = v;
    __syncthreads();
    for (int off = 1; off < 1024; off <<= 1) {
      int t = (tid >= off) ? ls[tid - off] : 0;
      __syncthreads();
      ls[tid] += t;
      __syncthreads();
    }
    if (i < N_) rowptr[i] = carry + ls[tid] - v;   // exclusive scan
    carry += ls[1023];
    __syncthreads();
  }
  if (tid == 0) rowptr[N_] = carry;
}

__global__ void k_fill(const int* __restrict__ dst, const int* __restrict__ rowptr,
                       int* __restrict__ cursor, int* __restrict__ cols) {
  int e = blockIdx.x * blockDim.x + threadIdx.x;
  if (e < E_) {
    int v = dst[e];
    int p = atomicAdd(&cursor[v], 1);
    cols[rowptr[v] + p] = e;
  }
}

__global__ void k_sumlog(const int* __restrict__ cnt, float* __restrict__ sumlog) {
  int i = blockIdx.x * blockDim.x + threadIdx.x;
  float v = (i < N_) ? logf((float)cnt[i] + 1.0f) : 0.0f;
  #pragma unroll
  for (int off = 32; off > 0; off >>= 1) v += __shfl_down(v, off);
  __shared__ float red[4];
  if ((threadIdx.x & 63) == 0) red[threadIdx.x >> 6] = v;
  __syncthreads();
  if (threadIdx.x == 0) atomicAdd(sumlog, red[0] + red[1] + red[2] + red[3]);
}

__global__ void k_scal(const int* __restrict__ cnt, const float* __restrict__ sumlog,
                       float* __restrict__ scal) {
  int i = blockIdx.x * blockDim.x + threadIdx.x;
  if (i >= N_) return;
  float c  = (float)cnt[i];
  float d  = fmaxf(c, 1.0f);
  float ld = logf(d + 1.0f);
  float avg_log = sumlog[0] * (1.0f / (float)N_);
  float avg_lin = (float)E_ / (float)N_;
  scal[i*4+0] = 1.0f;
  scal[i*4+1] = ld / avg_log;
  scal[i*4+2] = avg_log / ld;
  scal[i*4+3] = d / avg_lin;
}

// ---------------- per-layer prep ----------------
__global__ void k_edgevec(const float* __restrict__ pw, const float* __restrict__ pb,
                          const float* __restrict__ ew, const float* __restrict__ eb,
                          float* __restrict__ vec_e, float* __restrict__ cst_e, int f, int C) {
  int c = blockIdx.x * blockDim.x + threadIdx.x;
  if (c >= C) return;
  int t = c / f, g = c - t*f;
  const float* wp = pw + (size_t)t*3*f*f + (size_t)2*f*f + g;
  float v = 0.f, s = 0.f;
  for (int ff = 0; ff < f; ++ff) { float wv = wp[(size_t)ff*f]; v += ew[ff]*wv; s += eb[ff]*wv; }
  vec_e[c] = v;
  cst_e[c] = s + pb[c];
}

__global__ void k_pack_pre(const float* __restrict__ pw, float* __restrict__ Bp, int f, int C) {
  int idx = blockIdx.x * blockDim.x + threadIdx.x;
  int tot = f * 2 * C;
  if (idx >= tot) return;
  int k = idx / (2*C);
  int c = idx - k*(2*C);
  int half = c / C;
  int cc = c - half*C;
  int t = cc / f, g = cc - t*f;
  Bp[idx] = pw[(size_t)t*3*f*f + (size_t)(half*f + k)*f + g];
}

// Pack post weights transposed, bf16: W2[t][j=s*20+g][k], k in [0,KP).
// k<4f: w_s[t,k,g]; 4f<=k<5f (s==0 only): w_x[t,k-4f,g]; else 0.
__global__ void k_pack_w2(const float* __restrict__ qw, unsigned short* __restrict__ W2,
                          int f, int KP) {
  int tot = T_ * 80 * KP;
  int idx = blockIdx.x * blockDim.x + threadIdx.x;
  if (idx >= tot) return;
  int k = idx % KP;
  int r = idx / KP;
  int j = r % 80;
  int t = r / 80;
  int s = j / 20, g = j - s*20;
  float v = 0.f;
  if (k < 4*f)                 v = qw[((size_t)t*17*f + f + (size_t)s*4*f + k) * FO_ + g];
  else if (k < 5*f && s == 0)  v = qw[((size_t)t*17*f + (k - 4*f)) * FO_ + g];
  W2[idx] = f2bf(v);
}

// ---------------- generic tiled fp32 GEMM: C = A(MxK) @ B(KxNc) (+bias) ----------------
__global__ __launch_bounds__(256) void k_gemm(
    const float* __restrict__ A, const float* __restrict__ Bm,
    const float* __restrict__ bias, float* __restrict__ Cm,
    int M, int K, int Nc)
{
  __shared__ __align__(16) float As[16][68];
  __shared__ __align__(16) float Bs[16][64];
  const int tid = threadIdx.x;
  const int bm = blockIdx.x * 64;
  const int bn = blockIdx.y * 64;
  const int mg = tid & 15;
  const int ng = tid >> 4;
  float acc[4][4];
  #pragma unroll
  for (int i = 0; i < 4; ++i)
    #pragma unroll
    for (int j = 0; j < 4; ++j) acc[i][j] = 0.f;

  for (int k0 = 0; k0 < K; k0 += 16) {
    {
      int kk = tid & 15, mr = tid >> 4;
      #pragma unroll
      for (int p = 0; p < 4; ++p) {
        int m = mr + p*16;
        int gm = bm + m, gk = k0 + kk;
        As[kk][m] = (gm < M && gk < K) ? A[(size_t)gm*K + gk] : 0.f;
      }
      int nn = tid & 63, kr = tid >> 6;
      #pragma unroll
      for (int p = 0; p < 4; ++p) {
        int k = kr + p*4;
        int gk = k0 + k, gn = bn + nn;
        Bs[k][nn] = (gk < K && gn < Nc) ? Bm[(size_t)gk*Nc + gn] : 0.f;
      }
    }
    __syncthreads();
    #pragma unroll
    for (int kk = 0; kk < 16; ++kk) {
      const float4 a = *(const float4*)&As[kk][mg*4];
      const float4 b = *(const float4*)&Bs[kk][ng*4];
      const float av[4] = {a.x, a.y, a.z, a.w};
      const float bv[4] = {b.x, b.y, b.z, b.w};
      #pragma unroll
      for (int i = 0; i < 4; ++i)
        #pragma unroll
        for (int j = 0; j < 4; ++j)
          acc[i][j] = fmaf(av[i], bv[j], acc[i][j]);
    }
    __syncthreads();
  }
  #pragma unroll
  for (int i = 0; i < 4; ++i) {
    int gm = bm + mg*4 + i;
    if (gm >= M) continue;
    #pragma unroll
    for (int j = 0; j < 4; ++j) {
      int gn = bn + ng*4 + j;
      if (gn < Nc) {
        float v = acc[i][j];
        if (bias) v += bias[gn];
        Cm[(size_t)gm*Nc + gn] = v;
      }
    }
  }
}

// ---- variant: split output. gn<split -> fp32 XI[gm*split+gn]; gn>=split -> bf16 XJb ----
__global__ __launch_bounds__(256) void k_gemm2(
    const float* __restrict__ A, const float* __restrict__ Bm,
    float* __restrict__ XI, unsigned short* __restrict__ XJb,
    int M, int K, int Nc, int split)
{
  __shared__ __align__(16) float As[16][68];
  __shared__ __align__(16) float Bs[16][64];
  const int tid = threadIdx.x;
  const int bm = blockIdx.x * 64;
  const int bn = blockIdx.y * 64;
  const int mg = tid & 15;
  const int ng = tid >> 4;
  float acc[4][4];
  #pragma unroll
  for (int i = 0; i < 4; ++i)
    #pragma unroll
    for (int j = 0; j < 4; ++j) acc[i][j] = 0.f;

  for (int k0 = 0; k0 < K; k0 += 16) {
    {
      int kk = tid & 15, mr = tid >> 4;
      #pragma unroll
      for (int p = 0; p < 4; ++p) {
        int m = mr + p*16;
        int gm = bm + m, gk = k0 + kk;
        As[kk][m] = (gm < M && gk < K) ? A[(size_t)gm*K + gk] : 0.f;
      }
      int nn = tid & 63, kr = tid >> 6;
      #pragma unroll
      for (int p = 0; p < 4; ++p) {
        int k = kr + p*4;
        int gk = k0 + k, gn = bn + nn;
        Bs[k][nn] = (gk < K && gn < Nc) ? Bm[(size_t)gk*Nc + gn] : 0.f;
      }
    }
    __syncthreads();
    #pragma unroll
    for (int kk = 0; kk < 16; ++kk) {
      const float4 a = *(const float4*)&As[kk][mg*4];
      const float4 b = *(const float4*)&Bs[kk][ng*4];
      const float av[4] = {a.x, a.y, a.z, a.w};
      const float bv[4] = {b.x, b.y, b.z, b.w};
      #pragma unroll
      for (int i = 0; i < 4; ++i)
        #pragma unroll
        for (int j = 0; j < 4; ++j)
          acc[i][j] = fmaf(av[i], bv[j], acc[i][j]);
    }
    __syncthreads();
  }
  #pragma unroll
  for (int i = 0; i < 4; ++i) {
    int gm = bm + mg*4 + i;
    if (gm >= M) continue;
    #pragma unroll
    for (int j = 0; j < 4; ++j) {
      int gn = bn + ng*4 + j;
      if (gn < Nc) {
        float v = acc[i][j];
        if (gn < split) XI[(size_t)gm*split + gn] = v;
        else            XJb[(size_t)gm*split + (gn - split)] = f2bf(v);
      }
    }
  }
}

// ---------------- per-node aggregation -> bf16 Apost rows ----------------
// XJ gathered in bf16, 2 elems/dword/thread. Apost[n][t][k]: k<4f stats; [4f,5f) x; rest 0.
__global__ __launch_bounds__(256) void k_agg(
    const float* __restrict__ XI, const unsigned short* __restrict__ XJb,
    const int* __restrict__ rowptr,
    const int* __restrict__ cols, const int* __restrict__ srcArr,
    const float* __restrict__ ea, const float* __restrict__ vec_e,
    const float* __restrict__ cst_e, const float* __restrict__ xin,
    unsigned short* __restrict__ Apost, int f, int C, int KP)
{
  __shared__ float vsh[512];
  const int tid = threadIdx.x;
  for (int c = tid; c < C; c += 256) vsh[c] = vec_e[c];
  __syncthreads();
  const int v = blockIdx.x;
  const int start = rowptr[v], end = rowptr[v+1];
  const int half = C >> 1;                 // C even (T*f, f even)
  const bool act = (tid < half);
  const float v0 = act ? vsh[tid*2]   : 0.f;
  const float v1 = act ? vsh[tid*2+1] : 0.f;
  float s10 = 0.f, s11 = 0.f, s20 = 0.f, s21 = 0.f;
  float mn0 = 1e30f, mn1 = 1e30f, mx0 = -1e30f, mx1 = -1e30f;
  for (int p = start; p < end; ++p) {
    int e = cols[p];
    int s = srcArr[e];
    float a = ea[e];
    if (act) {
      unsigned int u = ((const unsigned int*)(XJb + (size_t)s * C))[tid];
      float y0 = fmaf(a, v0, bf2f_lo(u));
      float y1 = fmaf(a, v1, bf2f_hi(u));
      s10 += y0; s20 = fmaf(y0, y0, s20);
      s11 += y1; s21 = fmaf(y1, y1, s21);
      mn0 = fminf(mn0, y0); mx0 = fmaxf(mx0, y0);
      mn1 = fminf(mn1, y1); mx1 = fmaxf(mx1, y1);
    }
  }
  const int dcnt = end - start;
  if (act) {
    int c0 = tid*2;
    int t = c0 / f, ff = c0 - t*f;          // pair never straddles towers (f even)
    float base0 = XI[(size_t)v*C + c0]     + cst_e[c0];
    float base1 = XI[(size_t)v*C + c0 + 1] + cst_e[c0 + 1];
    float me0, sd0, lo0, hi0, me1, sd1, lo1, hi1;
    if (dcnt > 0) {
      float inv = 1.0f / (float)dcnt;
      float m10 = s10 * inv, m11 = s11 * inv;
      me0 = base0 + m10; me1 = base1 + m11;
      sd0 = sqrtf(fmaxf(s20*inv - m10*m10, 0.f) + EPSF);
      sd1 = sqrtf(fmaxf(s21*inv - m11*m11, 0.f) + EPSF);
      lo0 = base0 + mn0; hi0 = base0 + mx0;
      lo1 = base1 + mn1; hi1 = base1 + mx1;
    } else {
      me0 = me1 = lo0 = lo1 = hi0 = hi1 = 0.f;
      sd0 = sd1 = sqrtf(EPSF);
    }
    unsigned short* o = Apost + ((size_t)v * T_ + t) * KP + ff;
    o[0]     = f2bf(me0); o[1]       = f2bf(me1);
    o[f]     = f2bf(lo0); o[f+1]     = f2bf(lo1);
    o[2*f]   = f2bf(hi0); o[2*f+1]   = f2bf(hi1);
    o[3*f]   = f2bf(sd0); o[3*f+1]   = f2bf(sd1);
  }
  // x copy (shared by all towers) + zero pad
  const int rem = KP - 4*f;
  for (int idx = tid; idx < T_*rem; idx += 256) {
    int t = idx / rem, kk = idx - t*rem;
    int k = 4*f + kk;
    unsigned short val = 0;
    if (k < 5*f) val = f2bf(xin[(size_t)v*f + (k - 4*f)]);
    Apost[((size_t)v * T_ + t) * KP + k] = val;
  }
}

// ---------------- post GEMM via MFMA + fused scaler combine ----------------
// grid (ceil(N/128), T). 256 thr = 4 waves; wave w: rows [w*32,w*32+32),
// 2 m-frags x 5 n-frags 16x16, K-step 32. Epilogue: P tile -> LDS -> h.
__global__ __launch_bounds__(256) void k_postmm(
    const unsigned short* __restrict__ Apost, const unsigned short* __restrict__ W2,
    const float* __restrict__ scal, const float* __restrict__ qb,
    float* __restrict__ h, int KP)
{
  const int t    = blockIdx.y;
  const int m0   = blockIdx.x * 128;
  const int tid  = threadIdx.x;
  const int w    = tid >> 6;
  const int lane = tid & 63;
  const int rl   = lane & 15;     // frag row/col
  const int kq   = lane >> 4;     // k-quarter 0..3
  __shared__ __align__(16) unsigned char smem[128*84*4];   // 43008 B, reused
  unsigned short* As = (unsigned short*)smem;              // [128][40]
  unsigned short* Bs = As + 128*40;                        // [80][40]
  f32x4 acc[2][5];
  #pragma unroll
  for (int mf = 0; mf < 2; ++mf)
    #pragma unroll
    for (int nf = 0; nf < 5; ++nf) acc[mf][nf] = (f32x4){0.f,0.f,0.f,0.f};

  const unsigned short* wt = W2 + (size_t)t * 80 * KP;

  for (int k0 = 0; k0 < KP; k0 += 32) {
    __syncthreads();
    #pragma unroll
    for (int p = 0; p < 2; ++p) {
      int idx = tid + p*256;
      int row = idx >> 2, q = idx & 3;
      int gm = m0 + row;
      uint4 v = {0u,0u,0u,0u};
      if (gm < N_) v = *(const uint4*)&Apost[((size_t)gm*T_ + t)*KP + k0 + q*8];
      *(uint4*)&As[row*40 + q*8] = v;
    }
    #pragma unroll
    for (int p = 0; p < 2; ++p) {
      int idx = tid + p*256;
      if (idx < 320) {
        int j = idx >> 2, q = idx & 3;
        uint4 v = *(const uint4*)&wt[(size_t)j*KP + k0 + q*8];
        *(uint4*)&Bs[j*40 + q*8] = v;
      }
    }
    __syncthreads();
    short8 af[2], bf[5];
    #pragma unroll
    for (int mf = 0; mf < 2; ++mf)
      af[mf] = *(const short8*)&As[(w*32 + mf*16 + rl)*40 + kq*8];
    #pragma unroll
    for (int nf = 0; nf < 5; ++nf)
      bf[nf] = *(const short8*)&Bs[(nf*16 + rl)*40 + kq*8];
    #pragma unroll
    for (int mf = 0; mf < 2; ++mf)
      #pragma unroll
      for (int nf = 0; nf < 5; ++nf)
        acc[mf][nf] = __builtin_amdgcn_mfma_f32_16x16x32_bf16(af[mf], bf[nf], acc[mf][nf], 0, 0, 0);
  }
  // epilogue: P tile to LDS (C/D layout m89: col=lane&15, row=(lane>>4)*4+r)
  __syncthreads();
  float (*Pl)[84] = (float (*)[84])smem;
  #pragma unroll
  for (int mf = 0; mf < 2; ++mf)
    #pragma unroll
    for (int nf = 0; nf < 5; ++nf)
      #pragma unroll
      for (int r = 0; r < 4; ++r)
        Pl[w*32 + mf*16 + kq*4 + r][nf*16 + rl] = acc[mf][nf][r];
  __syncthreads();
  for (int idx = tid; idx < 128*FO_; idx += 256) {
    int row = idx / FO_, g = idx - row*FO_;
    int n = m0 + row;
    if (n < N_) {
      const float* p = Pl[row];
      float4 sc = *(const float4*)&scal[n*4];
      h[(size_t)n*(T_*FO_) + t*FO_ + g] =
        p[g] + sc.y*p[20+g] + sc.z*p[40+g] + sc.w*p[60+g] + qb[t*FO_+g];
    }
  }
}

// ---------------- batch norm ----------------
__global__ __launch_bounds__(256) void k_bnsum(const float* __restrict__ h2, float* __restrict__ bnsum) {
  const int tid  = threadIdx.x;
  const int c    = tid & 127;
  const int half = tid >> 7;
  if (c >= H_) return;
  float s = 0.f, s2 = 0.f;
  for (int r = blockIdx.x * 2 + half; r < N_; r += 256) {
    float v = h2[(size_t)r * H_ + c];
    s += v; s2 = fmaf(v, v, s2);
  }
  atomicAdd(&bnsum[c], s);
  atomicAdd(&bnsum[H_ + c], s2);
}

__global__ void k_bnapply(const float* __restrict__ h2, const float* __restrict__ bnsum,
                          const float* __restrict__ gam, const float* __restrict__ bet,
                          float* __restrict__ out) {
  size_t i = (size_t)blockIdx.x * blockDim.x + threadIdx.x;
  if (i >= (size_t)N_*H_) return;
  int c = (int)(i % H_);
  const float invn = 1.0f / (float)N_;
  float mu  = bnsum[c] * invn;
  float var = bnsum[H_ + c] * invn - mu*mu;
  float y = (h2[i] - mu) * rsqrtf(var + EPSF) * gam[c] + bet[c];
  out[i] = fmaxf(y, 0.f);
}

// ---------------- pooling + MLP ----------------
__global__ __launch_bounds__(256) void k_pool(const float* __restrict__ xc, const int* __restrict__ batch,
                                              float* __restrict__ gsum) {
  __shared__ float Pl[B_][H_];
  const int tid = threadIdx.x;
  for (int i = tid; i < B_*H_; i += 256) Pl[i / H_][i % H_] = 0.f;
  __syncthreads();
  const int r0 = blockIdx.x * PR_;
  const int rend = (r0 + PR_ < N_) ? r0 + PR_ : N_;
  const int nel = (rend - r0) * H_;
  for (int idx = tid; idx < nel; idx += 256) {
    int rr = idx / H_, c = idx - rr*H_;
    int n = r0 + rr;
    atomicAdd(&Pl[batch[n]][c], xc[(size_t)n*H_ + c]);
  }
  __syncthreads();
  const int blo = batch[r0], bhi = batch[rend-1];
  const int nb = (bhi - blo + 1) * H_;
  for (int idx = tid; idx < nb; idx += 256) {
    int b = blo + idx / H_, c = idx % H_;
    atomicAdd(&gsum[(size_t)b*H_ + c], Pl[b][c]);
  }
}

__global__ void k_gcnt(const int* __restrict__ batch, int* __restrict__ gcnt) {
  int n = blockIdx.x * blockDim.x + threadIdx.x;
  if (n < N_) atomicAdd(&gcnt[batch[n]], 1);
}

__global__ __launch_bounds__(512) void k_mlp(
    const float* __restrict__ gsum, const int* __restrict__ gcnt,
    const float* __restrict__ w1, const float* __restrict__ b1,
    const float* __restrict__ w2, const float* __restrict__ b2,
    const float* __restrict__ w3, const float* __restrict__ b3,
    float* __restrict__ out)
{
  __shared__ float G[B_][H_];
  __shared__ float A1[B_][50];
  __shared__ float A2[B_][25];
  const int tid = threadIdx.x;
  for (int i = tid; i < B_*H_; i += 512) {
    int r = i / H_;
    G[r][i - r*H_] = gsum[i] / fmaxf((float)gcnt[r], 1.0f);
  }
  __syncthreads();
  for (int i = tid; i < B_*50; i += 512) {
    int r = i / 50, c = i - r*50;
    float a = b1[c];
    for (int k = 0; k < H_; ++k) a = fmaf(G[r][k], w1[k*50 + c], a);
    A1[r][c] = fmaxf(a, 0.f);
  }
  __syncthreads();
  for (int i = tid; i < B_*25; i += 512) {
    int r = i / 25, c = i - r*25;
    float a = b2[c];
    for (int k = 0; k < 50; ++k) a = fmaf(A1[r][k], w2[k*25 + c], a);
    A2[r][c] = fmaxf(a, 0.f);
  }
  __syncthreads();
  for (int i = tid; i < B_; i += 512) {
    float a = b3[0];
    for (int k = 0; k < 25; ++k) a = fmaf(A2[i][k], w3[k], a);
    out[i] = a;   // float32 output — reference output dtype is f32
  }
}

// ---------------- host ----------------
extern "C" void kernel_launch(void* const* d_in, const int* in_sizes, int n_in,
                              void* d_out, int out_size, void* d_ws, size_t ws_size,
                              hipStream_t stream)
{
  (void)in_sizes; (void)n_in; (void)out_size;
  const float* x0   = (const float*)d_in[0];
  const int*   eidx = (const int*)  d_in[1];
  const float* ea   = (const float*)d_in[2];
  const int*   batch= (const int*)  d_in[3];
  const float* e0w  = (const float*)d_in[4];
  const float* e0b  = (const float*)d_in[5];
  const float* p0w  = (const float*)d_in[6];
  const float* p0b  = (const float*)d_in[7];
  const float* q0w  = (const float*)d_in[8];
  const float* q0b  = (const float*)d_in[9];
  const float* l0w  = (const float*)d_in[10];
  const float* l0b  = (const float*)d_in[11];
  const float* g0   = (const float*)d_in[12];
  const float* b0   = (const float*)d_in[13];
  const float* eLw  = (const float*)d_in[14];
  const float* eLb  = (const float*)d_in[15];
  const float* pLw  = (const float*)d_in[16];
  const float* pLb  = (const float*)d_in[17];
  const float* qLw  = (const float*)d_in[18];
  const float* qLb  = (const float*)d_in[19];
  const float* lLw  = (const float*)d_in[20];
  const float* lLb  = (const float*)d_in[21];
  const float* gL   = (const float*)d_in[22];
  const float* bL   = (const float*)d_in[23];
  const float* w1   = (const float*)d_in[24];
  const float* b1   = (const float*)d_in[25];
  const float* w2   = (const float*)d_in[26];
  const float* b2   = (const float*)d_in[27];
  const float* w3   = (const float*)d_in[28];
  const float* b3   = (const float*)d_in[29];

  const int* src = eidx;
  const int* dst = eidx + E_;

  char* w = (char*)d_ws;
  size_t off = 0;
  auto take = [&](size_t bytes) -> void* {
    void* p = (void*)(w + off);
    off = (off + bytes + 255) & ~(size_t)255;
    return p;
  };
  int*   cnt    = (int*)  take((size_t)N_*4);
  int*   rowptr = (int*)  take((size_t)(N_+1)*4);
  int*   cursor = (int*)  take((size_t)N_*4);
  int*   cols   = (int*)  take((size_t)E_*4);
  float* scal   = (float*)take((size_t)N_*16);
  float* sumlog = (float*)take(256);
  float* bnsum  = (float*)take((size_t)2*H_*4);
  float* vec_e  = (float*)take((size_t)T_*H_*4);
  float* cst_e  = (float*)take((size_t)T_*H_*4);
  float* Bpre   = (float*)take((size_t)H_*2*T_*H_*4);
  unsigned short* W2 = (unsigned short*)take((size_t)T_*80*512*2);
  float* XI     = (float*)take((size_t)N_*T_*H_*4);          // 40 MB
  unsigned short* XJb = (unsigned short*)take((size_t)N_*T_*H_*2);  // 20 MB
  unsigned short* Apost = (unsigned short*)take((size_t)N_*T_*512*2);  // 102 MB
  float* hbuf   = (float*)take((size_t)N_*H_*4);
  float* h2buf  = (float*)take((size_t)N_*H_*4);
  float* xcur   = (float*)take((size_t)N_*H_*4);
  float* gsum   = (float*)take((size_t)B_*H_*4);
  int*   gcnt   = (int*)  take((size_t)B_*4);
  if (off > ws_size) return;   // workspace too small: bail (test fails loudly)

  hipMemsetAsync(cnt,    0, (size_t)N_*4, stream);
  hipMemsetAsync(cursor, 0, (size_t)N_*4, stream);
  hipMemsetAsync(sumlog, 0, 4, stream);
  hipMemsetAsync(gsum,   0, (size_t)B_*H_*4, stream);
  hipMemsetAsync(gcnt,   0, (size_t)B_*4, stream);

  k_count <<<dim3((E_+255)/256), dim3(256), 0, stream>>>(dst, cnt);
  k_scan  <<<dim3(1),            dim3(1024),0, stream>>>(cnt, rowptr);
  k_fill  <<<dim3((E_+255)/256), dim3(256), 0, stream>>>(dst, rowptr, cursor, cols);
  k_sumlog<<<dim3((N_+255)/256), dim3(256), 0, stream>>>(cnt, sumlog);
  k_scal  <<<dim3((N_+255)/256), dim3(256), 0, stream>>>(cnt, sumlog, scal);

  auto layer = [&](const float* xin, int f,
                   const float* ew, const float* eb, const float* pw, const float* pb,
                   const float* qw, const float* qb, const float* lw, const float* lb,
                   const float* bg, const float* bb) {
    const int C  = T_ * f;
    const int KP = ((5*f + 31) / 32) * 32;   // padded per-tower K (f=16:96, f=100:512)
    k_edgevec<<<dim3((C+255)/256), dim3(256), 0, stream>>>(pw, pb, ew, eb, vec_e, cst_e, f, C);
    const int pe = f * 2 * C;
    k_pack_pre<<<dim3((pe+255)/256), dim3(256), 0, stream>>>(pw, Bpre, f, C);
    const int wtot = T_ * 80 * KP;
    k_pack_w2<<<dim3((wtot+255)/256), dim3(256), 0, stream>>>(qw, W2, f, KP);
    k_gemm2<<<dim3((N_+63)/64, (2*C+63)/64), dim3(256), 0, stream>>>(xin, Bpre, XI, XJb, N_, f, 2*C, C);
    k_agg<<<dim3(N_), dim3(256), 0, stream>>>(XI, XJb, rowptr, cols, src, ea, vec_e, cst_e, xin, Apost, f, C, KP);
    k_postmm<<<dim3((N_+127)/128, T_), dim3(256), 0, stream>>>(Apost, W2, scal, qb, hbuf, KP);
    k_gemm<<<dim3((N_+63)/64, (H_+63)/64), dim3(256), 0, stream>>>(hbuf, lw, lb, h2buf, N_, H_, H_);
    hipMemsetAsync(bnsum, 0, (size_t)2*H_*4, stream);
    k_bnsum<<<dim3(128), dim3(256), 0, stream>>>(h2buf, bnsum);
    k_bnapply<<<dim3((unsigned)(((size_t)N_*H_+255)/256)), dim3(256), 0, stream>>>(h2buf, bnsum, bg, bb, xcur);
  };

  layer(x0,   FI_, e0w, e0b, p0w, p0b, q0w, q0b, l0w, l0b, g0, b0);
  layer(xcur, H_,  eLw, eLb, pLw, pLb, qLw, qLb, lLw, lLb, gL, bL);
  layer(xcur, H_,  eLw + H_, eLb + H_,
        pLw + (size_t)T_*3*H_*H_, pLb + T_*H_,
        qLw + (size_t)T_*17*H_*FO_, qLb + T_*FO_,
        lLw + H_*H_, lLb + H_, gL + H_, bL + H_);

  k_pool<<<dim3((N_+PR_-1)/PR_), dim3(256), 0, stream>>>(xcur, batch, gsum);
  k_gcnt<<<dim3((N_+255)/256), dim3(256), 0, stream>>>(batch, gcnt);
  k_mlp <<<dim3(1), dim3(512), 0, stream>>>(gsum, gcnt, w1, b1, w2, b2, w3, b3, (float*)d_out);
}